// Round 4
// baseline (375.572 us; speedup 1.0000x reference)
//
#include <hip/hip_runtime.h>

#define BATCH 512
#define NN 256
#define MSZ (NN * NN)

typedef __attribute__((ext_vector_type(4))) float f32x4;

__device__ __forceinline__ float4 f4add(float4 x, float4 y) {
  return make_float4(x.x + y.x, x.y + y.y, x.z + y.z, x.w + y.w);
}

// Exact stable lexsort ranking: count of (t,v,idx) strictly less than self.
__device__ __forceinline__ void rank_side(const float* __restrict__ vv,
                                          const int* __restrict__ tt, int c,
                                          int* __restrict__ ordX) {
  const float vi = vv[c];
  const int ti = tt[c];
  int r = 0;
#pragma unroll 4
  for (int j = 0; j < NN; ++j) {
    const int tj = tt[j];
    const float vj = vv[j];
    const bool less =
        (tj < ti) || (tj == ti && (vj < vi || (vj == vi && j < c)));
    r += less ? 1 : 0;
  }
  ordX[r] = c;
}

// ---------------------------------------------------------------------------
// 2-batch pipelined block (256 blocks x 512 threads; 1 block/CU, 151 KB LDS).
// Per block, batches b0=2*bid, b1=b0+1:
//   A(b0): register-path column sums (bit-exact numpy pairwise association,
//          same chains/tree as all verified rounds). Waves 0,1 (which read
//          exactly D1 rows 0..127) additionally ds_write each loaded row into
//          a PERSISTENT 128 KB LDS region d1rows.
//   B(b0): combine tree + stable lexsort ranking -> plds (perm).
//   FUSED: C(b0) interleaved with A(b1): per m-step of A1's chains, two C0
//          row-iterations run. C0 rows with perm[i]<128 gather from d1rows
//          (no global read); others load the row from global (L3). C0's
//          writes and residual reads overlap A1's read-capped stream
//          (read & write per-CU paths are independent - phase-C evidence).
//   B(b1), then C(b1) standalone (full-global, 2-deep prefetch, nt stores).
// Per-CU read bytes: 512K(A0)+512K(A1)+~128K(C0)+256K(C1) = 1.38 MB
// vs 1.5 MB before, with C0 fully hidden -> ~128-133 us predicted.
// ---------------------------------------------------------------------------
__global__ __launch_bounds__(512, 2) void fused_pair_kernel(
    const float* __restrict__ D1, const float* __restrict__ D2,
    const int* __restrict__ t1, const int* __restrict__ t2,
    float* __restrict__ out, float* __restrict__ types_out) {
  const int b0 = 2 * blockIdx.x;
  const int b1 = b0 + 1;
  const int tid = threadIdx.x;
  const int lane = tid & 63;
  const int wv = tid >> 6;

  __shared__ __align__(16) char smem[154624];
  float* const d1rows = (float*)smem;               // [128][256] D1[b0] rows 0..127
  float* const partialf = (float*)(smem + 131072);  // [2][4][256]
  float* const va = (float*)(smem + 139264);
  float* const vb = (float*)(smem + 140288);
  int* const ta = (int*)(smem + 141312);
  int* const tb = (int*)(smem + 142336);
  int* const ord1 = (int*)(smem + 143360);
  int* const ord2 = (int*)(smem + 144384);
  int* const plds = (int*)(smem + 145408);
  float4* const rows = (float4*)(smem + 146432);    // [8][64]

  const int mat = wv >> 2;  // 0: D1, 1: D2
  const int s2 = wv & 3;    // h*2 + tq
  const int h = s2 >> 1;
  const int tq = s2 & 1;
  const int j0 = 4 * lane;

  // ================= Phase A(b0): chains + persist D1-h0 =================
  {
    const float* __restrict__ src = (mat ? D2 : D1) + (size_t)b0 * MSZ;
    const float* cb = src + (size_t)(h * 128 + 4 * tq) * NN + j0;
    const bool persist = (wv < 2);  // mat==0 && h==0: rows 4*tq+8m+k = 0..127
    float* const prow = d1rows + (size_t)(4 * tq) * NN + j0;

    float4 r0, r1, r2, r3;
#pragma unroll
    for (int m = 0; m < 16; ++m) {
      const float* p = cb + (size_t)(8 * m) * NN;
      const float4 v0 = *(const float4*)(p + (size_t)0 * NN);
      const float4 v1 = *(const float4*)(p + (size_t)1 * NN);
      const float4 v2 = *(const float4*)(p + (size_t)2 * NN);
      const float4 v3 = *(const float4*)(p + (size_t)3 * NN);
      if (persist) {
        float* q = prow + (size_t)(8 * m) * NN;
        *(float4*)(q + (size_t)0 * NN) = v0;
        *(float4*)(q + (size_t)1 * NN) = v1;
        *(float4*)(q + (size_t)2 * NN) = v2;
        *(float4*)(q + (size_t)3 * NN) = v3;
      }
      if (m == 0) { r0 = v0; r1 = v1; r2 = v2; r3 = v3; }
      else {
        r0 = f4add(r0, v0); r1 = f4add(r1, v1);
        r2 = f4add(r2, v2); r3 = f4add(r3, v3);
      }
    }
    const float4 part = f4add(f4add(r0, r1), f4add(r2, r3));
    *(float4*)(partialf + (size_t)(mat * 4 + s2) * NN + j0) = part;
  }
  __syncthreads();

  // ---- combine means b0 (exact tree) + stage types ----
  {
    const int cm = tid >> 8, c = tid & 255;
    const float p0 = partialf[(cm * 4 + 0) * NN + c];
    const float p1 = partialf[(cm * 4 + 1) * NN + c];
    const float p2 = partialf[(cm * 4 + 2) * NN + c];
    const float p3 = partialf[(cm * 4 + 3) * NN + c];
    const float mean = ((p0 + p1) + (p2 + p3)) * (1.0f / 256.0f);
    if (cm == 0) { va[c] = mean; ta[c] = t1[b0 * NN + c]; }
    else         { vb[c] = mean; tb[c] = t2[b0 * NN + c]; }
  }
  __syncthreads();
  // ---- rank b0 ----
  {
    const int side = tid >> 8, c = tid & 255;
    rank_side(side ? vb : va, side ? tb : ta, c, side ? ord2 : ord1);
  }
  __syncthreads();
  if (tid < NN) plds[ord2[tid]] = ord1[tid];
  __syncthreads();
  if (tid < NN) types_out[b0 * NN + tid] = (float)ta[plds[tid]];

  // ================= FUSED: C(b0) || A(b1) =================
  {
    const int pj0 = plds[j0 + 0];
    const int pj1 = plds[j0 + 1];
    const int pj2 = plds[j0 + 2];
    const int pj3 = plds[j0 + 3];
    const float* __restrict__ srcA = (mat ? D2 : D1) + (size_t)b1 * MSZ;
    const float* cbA = srcA + (size_t)(h * 128 + 4 * tq) * NN + j0;
    const float* __restrict__ Db0 = D1 + (size_t)b0 * MSZ;
    float* __restrict__ outb0 = out + (size_t)b0 * MSZ;
    float4* const roww = rows + wv * 64;
    const float* const rowf = (const float*)roww;

    auto c_iter = [&](int t) {
      const int i = t * 8 + wv;      // output row (wave-uniform)
      const int pi = plds[i];        // source row (wave-uniform)
      float4 o;
      if (pi < 128) {  // persistent: gather straight from LDS, no global read
        const float* base = d1rows + (size_t)pi * NN;
        o.x = base[pj0]; o.y = base[pj1]; o.z = base[pj2]; o.w = base[pj3];
      } else {
        const float4 v = *(const float4*)(Db0 + (size_t)pi * NN + j0);
        roww[lane] = v;  // wave-private; per-wave LDS ordering
        o.x = rowf[pj0]; o.y = rowf[pj1]; o.z = rowf[pj2]; o.w = rowf[pj3];
      }
      __builtin_nontemporal_store(*(const f32x4*)&o,
                                  (f32x4*)(outb0 + (size_t)i * NN + j0));
    };

    float4 q0 = *(const float4*)(cbA + (size_t)0 * NN);
    float4 q1 = *(const float4*)(cbA + (size_t)1 * NN);
    float4 q2 = *(const float4*)(cbA + (size_t)2 * NN);
    float4 q3 = *(const float4*)(cbA + (size_t)3 * NN);
    float4 r0, r1, r2, r3;
#pragma unroll
    for (int m = 0; m < 16; ++m) {
      c_iter(2 * m);
      if (m == 0) { r0 = q0; r1 = q1; r2 = q2; r3 = q3; }
      else {
        r0 = f4add(r0, q0); r1 = f4add(r1, q1);
        r2 = f4add(r2, q2); r3 = f4add(r3, q3);
      }
      if (m < 15) {  // issue next m-group loads; covered by c_iter below
        const float* p = cbA + (size_t)(8 * (m + 1)) * NN;
        q0 = *(const float4*)(p + (size_t)0 * NN);
        q1 = *(const float4*)(p + (size_t)1 * NN);
        q2 = *(const float4*)(p + (size_t)2 * NN);
        q3 = *(const float4*)(p + (size_t)3 * NN);
      }
      c_iter(2 * m + 1);
    }
    const float4 part = f4add(f4add(r0, r1), f4add(r2, r3));
    *(float4*)(partialf + (size_t)(mat * 4 + s2) * NN + j0) = part;
  }
  __syncthreads();

  // ---- combine means b1 + types ----
  {
    const int cm = tid >> 8, c = tid & 255;
    const float p0 = partialf[(cm * 4 + 0) * NN + c];
    const float p1 = partialf[(cm * 4 + 1) * NN + c];
    const float p2 = partialf[(cm * 4 + 2) * NN + c];
    const float p3 = partialf[(cm * 4 + 3) * NN + c];
    const float mean = ((p0 + p1) + (p2 + p3)) * (1.0f / 256.0f);
    if (cm == 0) { va[c] = mean; ta[c] = t1[b1 * NN + c]; }
    else         { vb[c] = mean; tb[c] = t2[b1 * NN + c]; }
  }
  __syncthreads();
  // ---- rank b1 ----
  {
    const int side = tid >> 8, c = tid & 255;
    rank_side(side ? vb : va, side ? tb : ta, c, side ? ord2 : ord1);
  }
  __syncthreads();
  if (tid < NN) plds[ord2[tid]] = ord1[tid];
  __syncthreads();
  if (tid < NN) types_out[b1 * NN + tid] = (float)ta[plds[tid]];

  // ================= C(b1): full-global, 2-deep prefetch =================
  {
    const int pj0 = plds[j0 + 0];
    const int pj1 = plds[j0 + 1];
    const int pj2 = plds[j0 + 2];
    const int pj3 = plds[j0 + 3];
    const float* __restrict__ Db1 = D1 + (size_t)b1 * MSZ;
    float* __restrict__ outb1 = out + (size_t)b1 * MSZ;
    float4* const roww = rows + wv * 64;
    const float* const rowf = (const float*)roww;

    float4 vA = *(const float4*)(Db1 + (size_t)plds[wv] * NN + j0);
    float4 vB = *(const float4*)(Db1 + (size_t)plds[8 + wv] * NN + j0);
#pragma unroll 4
    for (int it = 0; it < 32; ++it) {
      roww[lane] = vA;
      vA = vB;
      if (it + 2 < 32)
        vB = *(const float4*)(Db1 + (size_t)plds[(it + 2) * 8 + wv] * NN + j0);
      float4 o;
      o.x = rowf[pj0]; o.y = rowf[pj1]; o.z = rowf[pj2]; o.w = rowf[pj3];
      __builtin_nontemporal_store(*(const f32x4*)&o,
                                  (f32x4*)(outb1 + (size_t)(it * 8 + wv) * NN + j0));
    }
  }
}

extern "C" void kernel_launch(void* const* d_in, const int* in_sizes, int n_in,
                              void* d_out, int out_size, void* d_ws, size_t ws_size,
                              hipStream_t stream) {
  const float* D1 = (const float*)d_in[0];
  const float* D2 = (const float*)d_in[1];
  const int* t1 = (const int*)d_in[2];
  const int* t2 = (const int*)d_in[3];

  float* out = (float*)d_out;                        // [B,N,N] fp32
  float* types_out = out + (size_t)BATCH * NN * NN;  // [B,N] written as fp32

  fused_pair_kernel<<<BATCH / 2, 512, 0, stream>>>(D1, D2, t1, t2, out,
                                                   types_out);
}

// Round 5
// 352.886 us; speedup vs baseline: 1.0643x; 1.0643x over previous
//
#include <hip/hip_runtime.h>

#define BATCH 512
#define NN 256
#define MSZ (NN * NN)
#define PERSIST_ROWS 64

typedef __attribute__((ext_vector_type(4))) float f32x4;

// ---------------------------------------------------------------------------
// Phase-A chain helper: 16-step pairwise-summation chains for 4 rows/step,
// bit-exact numpy association (r_k serial over m ascending; (r0+r1)+(r2+r3)).
// NT: nontemporal loads (D2 only - read exactly once, keep L3 for D1).
// PERSIST: ds_write the loaded rows into the persistent d1rows region
// (waves 0-1, m<8 -> D1 rows 0..63 exactly; compile-time predicate).
// ---------------------------------------------------------------------------
template <bool NT, bool PERSIST>
__device__ __forceinline__ void chainsA(const float* __restrict__ cb,
                                        float* __restrict__ prow,
                                        float* __restrict__ partdst) {
  f32x4 r0, r1, r2, r3;
#pragma unroll
  for (int m = 0; m < 16; ++m) {
    const float* p = cb + (size_t)(8 * m) * NN;
    f32x4 v0, v1, v2, v3;
    if (NT) {
      v0 = __builtin_nontemporal_load((const f32x4*)(p + (size_t)0 * NN));
      v1 = __builtin_nontemporal_load((const f32x4*)(p + (size_t)1 * NN));
      v2 = __builtin_nontemporal_load((const f32x4*)(p + (size_t)2 * NN));
      v3 = __builtin_nontemporal_load((const f32x4*)(p + (size_t)3 * NN));
    } else {
      v0 = *(const f32x4*)(p + (size_t)0 * NN);
      v1 = *(const f32x4*)(p + (size_t)1 * NN);
      v2 = *(const f32x4*)(p + (size_t)2 * NN);
      v3 = *(const f32x4*)(p + (size_t)3 * NN);
    }
    if (PERSIST && m < 8) {  // rows 4*tq+8m+k = 0..63 across waves 0,1
      float* q = prow + (size_t)(8 * m) * NN;
      *(f32x4*)(q + (size_t)0 * NN) = v0;
      *(f32x4*)(q + (size_t)1 * NN) = v1;
      *(f32x4*)(q + (size_t)2 * NN) = v2;
      *(f32x4*)(q + (size_t)3 * NN) = v3;
    }
    if (m == 0) { r0 = v0; r1 = v1; r2 = v2; r3 = v3; }
    else        { r0 += v0; r1 += v1; r2 += v2; r3 += v3; }
  }
  *(f32x4*)partdst = (r0 + r1) + (r2 + r3);
}

// Exact stable lexsort ranking: count of (t,v,idx) strictly less than self.
__device__ __forceinline__ void rank_side(const float* __restrict__ vv,
                                          const int* __restrict__ tt, int c,
                                          int* __restrict__ ordX) {
  const float vi = vv[c];
  const int ti = tt[c];
  int r = 0;
#pragma unroll 4
  for (int j = 0; j < NN; ++j) {
    const int tj = tt[j];
    const float vj = vv[j];
    const bool less =
        (tj < ti) || (tj == ti && (vj < vi || (vj == vi && j < c)));
    r += less ? 1 : 0;
  }
  ordX[r] = c;
}

// ---------------------------------------------------------------------------
// FUSED kernel (round-2 structure, proven 145 us): 512 blocks x 512 threads,
// one batch per block, 76 KB LDS -> 2 blocks/CU.
// LDS map (bytes), time-sliced:
//   [0,      65536): d1rows [64][256]  — D1 rows 0..63, persists A -> C
//   [65536,  73728): partialf [2][4][256]      (phase A/combine)
//        reused:  ord1@65536 ord2@66560 plds@67584 rows[8][64]f4@68608
//   [73728,  77824): va vb ta tb                (combine/rank; ta->types)
// Phase A: register-path chains (bit-exact association, same as all verified
//   rounds). D2 side uses nontemporal loads (read-once; biases 256MB L3
//   toward D1, which phase C re-reads). Waves 0-1 persist D1 rows 0..63.
// Phase B: combine tree + stable lexsort ranking (unchanged).
// Phase C: out[b,i,j] = D1[b,perm[i],perm[j]]. Rows with perm[i]<64 gather
//   straight from LDS (25% fewer reads -> C becomes purely write-bound);
//   others: 1-deep prefetched global row -> LDS bounce -> gather; nt stores.
// ---------------------------------------------------------------------------
__global__ __launch_bounds__(512, 2) void fused_hungarian_kernel(
    const float* __restrict__ D1, const float* __restrict__ D2,
    const int* __restrict__ t1, const int* __restrict__ t2,
    float* __restrict__ out, float* __restrict__ types_out) {
  const int b = blockIdx.x;
  const int tid = threadIdx.x;
  const int lane = tid & 63;
  const int wv = tid >> 6;

  __shared__ __align__(16) char smem[77824];
  float* const d1rows = (float*)smem;                // [64][256]
  float* const partialf = (float*)(smem + 65536);    // [2][4][256]
  int* const ord1 = (int*)(smem + 65536);
  int* const ord2 = (int*)(smem + 66560);
  int* const plds = (int*)(smem + 67584);
  float4* const rows = (float4*)(smem + 68608);      // [8][64]
  float* const va = (float*)(smem + 73728);
  float* const vb = (float*)(smem + 74752);
  int* const ta = (int*)(smem + 75776);
  int* const tb = (int*)(smem + 76800);

  const int mat = wv >> 2;  // 0: D1, 1: D2
  const int s2 = wv & 3;    // h*2 + tq
  const int h = s2 >> 1;
  const int tq = s2 & 1;
  const int j0 = 4 * lane;

  // ================= Phase A: chains + persist D1 rows 0..63 =============
  {
    const float* __restrict__ src = (mat ? D2 : D1) + (size_t)b * MSZ;
    const float* cb = src + (size_t)(h * 128 + 4 * tq) * NN + j0;
    float* const prow = d1rows + (size_t)(4 * tq) * NN + j0;
    float* const pdst = partialf + (size_t)(mat * 4 + s2) * NN + j0;

    if (wv < 2)            chainsA<false, true>(cb, prow, pdst);   // D1, h=0
    else if (mat == 0)     chainsA<false, false>(cb, prow, pdst);  // D1, h=1
    else                   chainsA<true, false>(cb, prow, pdst);   // D2 (nt)
  }
  __syncthreads();

  // ---- combine means (exact tree) + stage types ----
  {
    const int cm = tid >> 8, c = tid & 255;
    const float p0 = partialf[(cm * 4 + 0) * NN + c];
    const float p1 = partialf[(cm * 4 + 1) * NN + c];
    const float p2 = partialf[(cm * 4 + 2) * NN + c];
    const float p3 = partialf[(cm * 4 + 3) * NN + c];
    // (p0+p1) = half0, (p2+p3) = half1; tot = half0 + half1; /256 exact
    const float mean = ((p0 + p1) + (p2 + p3)) * (1.0f / 256.0f);
    if (cm == 0) { va[c] = mean; ta[c] = t1[b * NN + c]; }
    else         { vb[c] = mean; tb[c] = t2[b * NN + c]; }
  }
  __syncthreads();

  // ---- rank both sides concurrently (partialf region now dead) ----
  {
    const int side = tid >> 8, c = tid & 255;
    rank_side(side ? vb : va, side ? tb : ta, c, side ? ord2 : ord1);
  }
  __syncthreads();
  if (tid < NN) plds[ord2[tid]] = ord1[tid];  // perm[ord2[k]] = ord1[k]
  __syncthreads();
  if (tid < NN) types_out[b * NN + tid] = (float)ta[plds[tid]];

  // ================= Phase C: symmetric reorder =================
  {
    const int pj0 = plds[j0 + 0];
    const int pj1 = plds[j0 + 1];
    const int pj2 = plds[j0 + 2];
    const int pj3 = plds[j0 + 3];
    const float* __restrict__ Db = D1 + (size_t)b * MSZ;
    float* __restrict__ outb = out + (size_t)b * MSZ;
    float4* const roww = rows + wv * 64;
    const float* const rowf = (const float*)roww;

    // 1-deep software pipeline over this wave's 32 rows (i = it*8 + wv)
    int pi_cur = plds[wv];
    bool g_cur = pi_cur >= PERSIST_ROWS;
    float4 v_cur;
    if (g_cur) v_cur = *(const float4*)(Db + (size_t)pi_cur * NN + j0);

#pragma unroll 4
    for (int it = 0; it < 32; ++it) {
      // prefetch next row
      int pi_nxt = 0;
      bool g_nxt = false;
      float4 v_nxt;
      if (it < 31) {
        pi_nxt = plds[(it + 1) * 8 + wv];
        g_nxt = pi_nxt >= PERSIST_ROWS;
        if (g_nxt) v_nxt = *(const float4*)(Db + (size_t)pi_nxt * NN + j0);
      }
      float4 o;
      if (g_cur) {
        roww[lane] = v_cur;  // wave-private bounce; same-wave LDS ordering
        o.x = rowf[pj0]; o.y = rowf[pj1]; o.z = rowf[pj2]; o.w = rowf[pj3];
      } else {
        const float* base = d1rows + (size_t)pi_cur * NN;
        o.x = base[pj0]; o.y = base[pj1]; o.z = base[pj2]; o.w = base[pj3];
      }
      __builtin_nontemporal_store(
          *(const f32x4*)&o,
          (f32x4*)(outb + (size_t)(it * 8 + wv) * NN + j0));
      pi_cur = pi_nxt; g_cur = g_nxt; v_cur = v_nxt;
    }
  }
}

extern "C" void kernel_launch(void* const* d_in, const int* in_sizes, int n_in,
                              void* d_out, int out_size, void* d_ws, size_t ws_size,
                              hipStream_t stream) {
  const float* D1 = (const float*)d_in[0];
  const float* D2 = (const float*)d_in[1];
  const int* t1 = (const int*)d_in[2];
  const int* t2 = (const int*)d_in[3];

  float* out = (float*)d_out;                        // [B,N,N] fp32
  float* types_out = out + (size_t)BATCH * NN * NN;  // [B,N] written as fp32

  fused_hungarian_kernel<<<BATCH, 512, 0, stream>>>(D1, D2, t1, t2, out,
                                                    types_out);
}